// Round 8
// baseline (618.580 us; speedup 1.0000x reference)
//
#include <hip/hip_runtime.h>

// VectorQuantizer: z [16,1024,512] f32, emb [8192,512] f32
// out: [z_q_st (16384*512 f32)][total_loss (1 f32)][idx as f32 (16384)]
//
// bf16 MFMA computes approx dot(z,emb) (argmax acc == argmin dist); epilogue keeps
// per-(row,256-tile) max + candidates within MARGIN_A; finalize rechecks candidates
// with the EXACT fp32 d-ascending fmaf chain + q = fl(s1-2*dot) quantization
// (bit-identical to the round-2 kernel that passed absmax 0), lowest-index ties.
//
// Round 8: latency-model fix. Stage feed was outstanding-limited (~6 gloads/wave
// in flight => 2.6-4.8 TB/s observed). Ring-of-3 K-tile buffers (144KB LDS),
// stage issued TWO tiles ahead (12 gloads/wave in flight), ONE s_barrier per
// K-step, counted vmcnt(6) (drain 0 only at the end). Issue-after-read-barrier
// makes ring overwrites safe.

#define N_TOK 16384
#define DIM   512
#define NEMB  8192
#define BETA  0.25f
#define NKT   32              // 8192 / 256 n-tiles
#define MARGIN_A 2.0e-4f      // in acc(dot) units; plateau 3.05e-5 + bf16 err (14-sigma)

using short8 = __attribute__((ext_vector_type(8))) short;
using f32x4  = __attribute__((ext_vector_type(4))) float;

// ---- ws layout (bytes), total ~46.2 MB ----
#define WS_ACC  0
#define WS_CNT  64
#define WS_PMAX (WS_CNT  + N_TOK*NKT*4)
#define WS_PIDX (WS_PMAX + N_TOK*NKT*4)
#define WS_EXTK (WS_PIDX + N_TOK*NKT*4)
#define WS_S1   (WS_EXTK + N_TOK*NKT*7*4)
#define WS_ZH   (WS_S1   + N_TOK*4)
#define WS_EH   (WS_ZH   + N_TOK*DIM*2)

__device__ inline short f2bf(float f) {   // RNE float->bf16
  unsigned u = __builtin_bit_cast(unsigned, f);
  u += 0x7fffu + ((u >> 16) & 1u);
  return (short)(u >> 16);
}

#define GLDS16(g, l) __builtin_amdgcn_global_load_lds( \
    (const __attribute__((address_space(1))) void*)(g), \
    (__attribute__((address_space(3))) void*)(l), 16, 0, 0)

// pack z -> zh bf16 fragment layout [mt(128)][kc(64)][mi(128)][j(8)], fused s1.
__global__ void vq_pack_z(const float* __restrict__ z, short* __restrict__ zh,
                          float* __restrict__ s1) {
  const int w = threadIdx.x >> 6, lane = threadIdx.x & 63;
  const int row = blockIdx.x * 4 + w;
  const float4* r = (const float4*)(z + (size_t)row * DIM);
  float4 v0 = r[lane * 2], v1 = r[lane * 2 + 1];
  // s1: bit-identical to the passing round-2 path (same products, order, reduce)
  float p0=v0.x*v0.x, p1=v0.y*v0.y, p2=v0.z*v0.z, p3=v0.w*v0.w;
  float p4=v1.x*v1.x, p5=v1.y*v1.y, p6=v1.z*v1.z, p7=v1.w*v1.w;
  double s = (double)p0+(double)p1+(double)p2+(double)p3
           + (double)p4+(double)p5+(double)p6+(double)p7;
  #pragma unroll
  for (int m = 32; m >= 1; m >>= 1) s += __shfl_xor(s, m);
  if (lane == 0) s1[row] = (float)s;
  short8 o;
  o[0]=f2bf(v0.x); o[1]=f2bf(v0.y); o[2]=f2bf(v0.z); o[3]=f2bf(v0.w);
  o[4]=f2bf(v1.x); o[5]=f2bf(v1.y); o[6]=f2bf(v1.z); o[7]=f2bf(v1.w);
  const int mt = row >> 7, mi = row & 127;          // kc == lane
  *(short8*)(zh + ((((size_t)mt * 64 + lane) * 128) + mi) * 8) = o;
}

// pack emb -> eh bf16 fragment layout [nt(32)][kc(64)][ni(256)][j(8)], wave-per-row.
__global__ void vq_pack_e(const float* __restrict__ e, short* __restrict__ eh) {
  const int w = threadIdx.x >> 6, lane = threadIdx.x & 63;
  const int row = blockIdx.x * 4 + w;
  const float4* r = (const float4*)(e + (size_t)row * DIM);
  float4 v0 = r[lane * 2], v1 = r[lane * 2 + 1];
  short8 o;
  o[0]=f2bf(v0.x); o[1]=f2bf(v0.y); o[2]=f2bf(v0.z); o[3]=f2bf(v0.w);
  o[4]=f2bf(v1.x); o[5]=f2bf(v1.y); o[6]=f2bf(v1.z); o[7]=f2bf(v1.w);
  const int nt = row >> 8, ni = row & 255;
  *(short8*)(eh + ((((size_t)nt * 64 + lane) * 256) + ni) * 8) = o;
}

// MFMA GEMM + fused argmax/candidate epilogue.
// Block = 128 rows x 256 cols, 8 waves (2m x 4n), wave tile 64x64, BK=64,
// ring-of-3 K-tile LDS (144KB), stage 2 tiles ahead, 1 barrier + vmcnt(6)/step.
__global__ __launch_bounds__(512, 1)
void vq_mfma(const short* __restrict__ zh, const short* __restrict__ eh,
             float* __restrict__ pmax, int* __restrict__ pidx,
             int* __restrict__ cnt, int* __restrict__ extk) {
  __shared__ short8 lA[3][8 * 128];   // 3 x 16KB
  __shared__ short8 lB[3][8 * 256];   // 3 x 32KB

  // XCD-chunked swizzle (bijective: 4096 = 8*16*32)
  const int bid = blockIdx.x;
  const int c = bid & 7, pos = bid >> 3;
  const int mt = c * 16 + (pos & 15), nt = pos >> 4;

  const int n0 = nt * 256, m0 = mt * 128;
  const int tid = threadIdx.x;
  const int wid = tid >> 6, lane = tid & 63;
  const int wm = wid >> 2, wn = wid & 3;
  const int quad = lane >> 4, lc = lane & 15;

  f32x4 C[4][4];
  #pragma unroll
  for (int i = 0; i < 4; ++i)
    #pragma unroll
    for (int j = 0; j < 4; ++j) C[i][j] = (f32x4){0.f, 0.f, 0.f, 0.f};

  const char* gA = (const char*)zh + (size_t)mt * 131072;  // 64kc*128mi*16B panel
  const char* gB = (const char*)eh + (size_t)nt * 262144;  // 64kc*256ni*16B panel

  // stage K-tile t into ring slot: A 16 chunks + B 32 chunks of 1KB; 6/wave.
  auto stage = [&](int slot, int t) {
    const char* a = gA + (size_t)t * 16384;
    const char* b = gB + (size_t)t * 32768;
    #pragma unroll
    for (int i = 0; i < 6; ++i) {
      const int ch = wid * 6 + i;
      if (ch < 16) GLDS16(a + ch * 1024 + lane * 16, (char*)&lA[slot][0] + ch * 1024);
      else         GLDS16(b + (ch - 16) * 1024 + lane * 16, (char*)&lB[slot][0] + (ch - 16) * 1024);
    }
  };

  stage(0, 0);                                  // 6 in flight
  stage(1, 1);                                  // 12 in flight
  asm volatile("s_waitcnt vmcnt(6)" ::: "memory");   // tile0 landed
  __builtin_amdgcn_s_barrier();

  #pragma unroll
  for (int t = 0; t < 8; ++t) {
    if (t + 2 < 8) stage((t + 2) % 3, t + 2);   // slot (t+2)%3 last read in iter t-1
    const int sl = t % 3;
    #pragma unroll
    for (int s = 0; s < 2; ++s) {               // two K=32 slots per BK=64 tile
      const int kx = s * 4 + quad;
      short8 a[4], b[4];
      #pragma unroll
      for (int mf = 0; mf < 4; ++mf) a[mf] = lA[sl][kx * 128 + wm * 64 + mf * 16 + lc];
      #pragma unroll
      for (int nf = 0; nf < 4; ++nf) b[nf] = lB[sl][kx * 256 + wn * 64 + nf * 16 + lc];
      __builtin_amdgcn_s_setprio(1);
      #pragma unroll
      for (int mf = 0; mf < 4; ++mf)
        #pragma unroll
        for (int nf = 0; nf < 4; ++nf)
          C[mf][nf] = __builtin_amdgcn_mfma_f32_16x16x32_bf16(a[mf], b[nf],
                                                              C[mf][nf], 0, 0, 0);
      __builtin_amdgcn_s_setprio(0);
    }
    // retire next tile's loads; keep the tile-after's 6 in flight
    if (t < 6)      asm volatile("s_waitcnt vmcnt(6)" ::: "memory");
    else if (t == 6) asm volatile("s_waitcnt vmcnt(0)" ::: "memory");
    if (t < 7) __builtin_amdgcn_s_barrier();
  }
  __builtin_amdgcn_s_barrier();                 // K-loop reads done; LDS reusable

  // ---- epilogue (aliases lA; proven absmax-0 machinery) ----
  float* cmbv = (float*)&lA[0][0];              // [128][4]
  int*   cmbk = (int*)(cmbv + 512);
  float* bbv  = (float*)(cmbk + 512);
  int*   bbk  = (int*)(bbv + 128);

  // per-row argmax over this 256-wide tile; C/D layout: row=quad*4+rr, col=lc
  #pragma unroll
  for (int mf = 0; mf < 4; ++mf)
    #pragma unroll
    for (int rr = 0; rr < 4; ++rr) {
      float bv = C[mf][0][rr]; int bn = 0;
      #pragma unroll
      for (int nf = 1; nf < 4; ++nf) {
        float v = C[mf][nf][rr];
        if (v > bv) { bv = v; bn = nf; }        // strict >: ties -> lowest nf (lowest k)
      }
      int bk = n0 + wn * 64 + bn * 16 + lc;
      #pragma unroll
      for (int m = 8; m >= 1; m >>= 1) {        // reduce 16 lanes (same quad)
        float vo = __shfl_xor(bv, m); int ko = __shfl_xor(bk, m);
        if (vo > bv || (vo == bv && ko < bk)) { bv = vo; bk = ko; }
      }
      if (lc == 0) {
        int row = wm * 64 + mf * 16 + quad * 4 + rr;
        cmbv[row * 4 + wn] = bv; cmbk[row * 4 + wn] = bk;
      }
    }
  __syncthreads();
  if (tid < 128) {
    float bv = cmbv[tid * 4 + 0]; int bk = cmbk[tid * 4 + 0];
    #pragma unroll
    for (int q = 1; q < 4; ++q) {               // ascending wn => ascending k: strict >
      float v = cmbv[tid * 4 + q]; int k = cmbk[tid * 4 + q];
      if (v > bv) { bv = v; bk = k; }
    }
    bbv[tid] = bv; bbk[tid] = bk;
    size_t rg = (size_t)(m0 + tid) * NKT + nt;
    pmax[rg] = bv; pidx[rg] = bk;
  }
  __syncthreads();
  // emit near-max extras
  #pragma unroll
  for (int mf = 0; mf < 4; ++mf)
    #pragma unroll
    for (int nf = 0; nf < 4; ++nf)
      #pragma unroll
      for (int rr = 0; rr < 4; ++rr) {
        int row = wm * 64 + mf * 16 + quad * 4 + rr;
        float v = C[mf][nf][rr];
        if (v >= bbv[row] - MARGIN_A) {
          int k = n0 + wn * 64 + nf * 16 + lc;
          if (k != bbk[row]) {
            size_t rg = (size_t)(m0 + row) * NKT + nt;
            int slot = atomicAdd(&cnt[rg], 1);
            if (slot < 7) extk[rg * 7 + slot] = k;
          }
        }
      }
}

// per-row: pick candidate tiles, EXACT fp32 recheck, gather/outputs/loss (unchanged)
__global__ void vq_finalize(const float* __restrict__ z, const float* __restrict__ emb,
                            const float* __restrict__ s1g,
                            const float* __restrict__ pmax, const int* __restrict__ pidx,
                            const int* __restrict__ cnt, const int* __restrict__ extk,
                            float* __restrict__ out, double* __restrict__ acc) {
  __shared__ int candk[4][40];
  __shared__ int lcnt[4];
  const int w = threadIdx.x >> 6, l = threadIdx.x & 63;
  const int row = blockIdx.x * 4 + w;
  const int l5 = l & 31;
  if (l == 0) lcnt[w] = 0;
  __syncthreads();
  const size_t rb = (size_t)row * NKT;
  float pv = pmax[rb + l5]; int pk = pidx[rb + l5];
  float gv = pv; int gk = pk;
  #pragma unroll
  for (int m = 16; m >= 1; m >>= 1) {
    float vo = __shfl_xor(gv, m); int ko = __shfl_xor(gk, m);
    if (vo > gv || (vo == gv && ko < gk)) { gv = vo; gk = ko; }
  }
  if (l < 32 && pv >= gv - MARGIN_A) {
    int c = cnt[rb + l5]; if (c > 7) c = 7;
    int slot = atomicAdd(&lcnt[w], 1 + c);
    if (slot < 40) candk[w][slot] = pk;
    for (int i = 0; i < c; ++i)
      if (slot + 1 + i < 40) candk[w][slot + 1 + i] = extk[(rb + l5) * 7 + i];
  }
  __syncthreads();
  int Cc = lcnt[w]; if (Cc > 40) Cc = 40;
  float qb = 1e30f; int kb = 0x7fffffff;
  const float s1 = s1g[row];
  const float* zr = z + (size_t)row * DIM;
  for (int ci = l5; ci < Cc; ci += 32) {    // lanes 32-63 duplicate (harmless)
    int k = candk[w][ci];
    const float* er = emb + (size_t)k * DIM;
    float d = 0.f;
    for (int i = 0; i < DIM; ++i) d = fmaf(zr[i], er[i], d);  // strict d-ascending
    float q = s1 - 2.f * d;                  // single-rounding quantize (2*d exact)
    if (q < qb || (q == qb && k < kb)) { qb = q; kb = k; }
  }
  #pragma unroll
  for (int m = 32; m >= 1; m >>= 1) {
    float qo = __shfl_xor(qb, m); int ko = __shfl_xor(kb, m);
    if (qo < qb || (qo == qb && ko < kb)) { qb = qo; kb = ko; }
  }
  const float4* zr4 = (const float4*)zr;
  const float4* qr4 = (const float4*)(emb + (size_t)kb * DIM);
  float4 zv0 = zr4[l * 2], zv1 = zr4[l * 2 + 1];
  float4 qv0 = qr4[l * 2], qv1 = qr4[l * 2 + 1];
  float ls = 0.f; float4 ov0, ov1;
  {
    const float* zp=(const float*)&zv0; const float* qp=(const float*)&qv0; float* op=(float*)&ov0;
    #pragma unroll
    for (int e = 0; e < 4; ++e) { float d = qp[e]-zp[e]; op[e] = zp[e]+d; ls += d*d; }
  }
  {
    const float* zp=(const float*)&zv1; const float* qp=(const float*)&qv1; float* op=(float*)&ov1;
    #pragma unroll
    for (int e = 0; e < 4; ++e) { float d = qp[e]-zp[e]; op[e] = zp[e]+d; ls += d*d; }
  }
  float4* orow = (float4*)(out + (size_t)row * DIM);
  orow[l * 2] = ov0; orow[l * 2 + 1] = ov1;
  #pragma unroll
  for (int m = 32; m >= 1; m >>= 1) ls += __shfl_xor(ls, m);
  if (l == 0) {
    out[(size_t)N_TOK * DIM + 1 + row] = (float)kb;
    atomicAdd(acc, (double)ls);
  }
}

__global__ void vq_loss(const double* __restrict__ acc, float* __restrict__ out) {
  out[(size_t)N_TOK * DIM] =
      (float)(*acc * (1.0 + (double)BETA) / ((double)N_TOK * (double)DIM));
}

extern "C" void kernel_launch(void* const* d_in, const int* in_sizes, int n_in,
                              void* d_out, int out_size, void* d_ws, size_t ws_size,
                              hipStream_t stream) {
  const float* z   = (const float*)d_in[0];
  const float* emb = (const float*)d_in[1];
  float* out = (float*)d_out;
  char* ws = (char*)d_ws;
  double* acc  = (double*)(ws + WS_ACC);
  int*    cnt  = (int*)(ws + WS_CNT);
  float*  pmax = (float*)(ws + WS_PMAX);
  int*    pidx = (int*)(ws + WS_PIDX);
  int*    extk = (int*)(ws + WS_EXTK);
  float*  s1   = (float*)(ws + WS_S1);
  short*  zh   = (short*)(ws + WS_ZH);
  short*  eh   = (short*)(ws + WS_EH);

  hipMemsetAsync(ws, 0, WS_CNT + (size_t)N_TOK * NKT * 4, stream);  // acc + cnt
  vq_pack_z<<<N_TOK / 4, 256, 0, stream>>>(z, zh, s1);
  vq_pack_e<<<NEMB / 4, 256, 0, stream>>>(emb, eh);
  vq_mfma<<<(N_TOK / 128) * (NEMB / 256), 512, 0, stream>>>(zh, eh, pmax, pidx, cnt, extk);
  vq_finalize<<<N_TOK / 4, 256, 0, stream>>>(z, emb, s1, pmax, pidx, cnt, extk, out, acc);
  vq_loss<<<1, 1, 0, stream>>>(acc, out);
}

// Round 9
// 541.119 us; speedup vs baseline: 1.1431x; 1.1431x over previous
//
#include <hip/hip_runtime.h>

// VectorQuantizer: z [16,1024,512] f32, emb [8192,512] f32
// out: [z_q_st (16384*512 f32)][total_loss (1 f32)][idx as f32 (16384)]
//
// bf16 MFMA computes approx dot(z,emb) (argmax acc == argmin dist); epilogue keeps
// per-(row,256-tile) max + candidates within MARGIN_A; finalize rechecks candidates
// with the EXACT fp32 d-ascending fmaf chain + q = fl(s1-2*dot) quantization
// (bit-identical to the round-2 kernel that passed absmax 0), lowest-index ties.
//
// Round 9: faithful 8-phase-style schedule (m201 template). 256x256 tile, BK=64,
// 8 waves, dbuf 128KB LDS. 4 phases per K-tile; each phase interleaves
// {8 ds_read_b128 | 2 global_load_lds} -> barrier -> lgkmcnt(0)+sched_barrier ->
// setprio(1) 16 MFMA setprio(0) -> [vmcnt(4) at odd phases, never 0 mid-loop]
// -> barrier. Candidate counters moved to LDS; cnt plain-stored (no memset).

#define N_TOK 16384
#define DIM   512
#define NEMB  8192
#define BETA  0.25f
#define NKT   32              // 8192 / 256 n-tiles
#define MARGIN_A 2.0e-4f      // in acc(dot) units; plateau 3.05e-5 + bf16 err (14-sigma)

using short8 = __attribute__((ext_vector_type(8))) short;
using f32x4  = __attribute__((ext_vector_type(4))) float;

// ---- ws layout (bytes), total ~46.2 MB ----
#define WS_ACC  0
#define WS_CNT  64
#define WS_PMAX (WS_CNT  + N_TOK*NKT*4)
#define WS_PIDX (WS_PMAX + N_TOK*NKT*4)
#define WS_EXTK (WS_PIDX + N_TOK*NKT*4)
#define WS_S1   (WS_EXTK + N_TOK*NKT*7*4)
#define WS_ZH   (WS_S1   + N_TOK*4)
#define WS_EH   (WS_ZH   + N_TOK*DIM*2)

__device__ inline short f2bf(float f) {   // RNE float->bf16
  unsigned u = __builtin_bit_cast(unsigned, f);
  u += 0x7fffu + ((u >> 16) & 1u);
  return (short)(u >> 16);
}

#define GLDS16(g, l) __builtin_amdgcn_global_load_lds( \
    (const __attribute__((address_space(1))) void*)(g), \
    (__attribute__((address_space(3))) void*)(l), 16, 0, 0)

// pack z -> zh bf16 fragment layout [mt(64)][kc(64)][mi(256)][j(8)], fused s1.
// Also zeroes the loss accumulator (block 0, thread 0) -- replaces the memset.
__global__ void vq_pack_z(const float* __restrict__ z, short* __restrict__ zh,
                          float* __restrict__ s1, double* __restrict__ acc) {
  if (blockIdx.x == 0 && threadIdx.x == 0) *acc = 0.0;
  const int w = threadIdx.x >> 6, lane = threadIdx.x & 63;
  const int row = blockIdx.x * 4 + w;
  const float4* r = (const float4*)(z + (size_t)row * DIM);
  float4 v0 = r[lane * 2], v1 = r[lane * 2 + 1];
  // s1: bit-identical to the passing round-2 path (same products, order, reduce)
  float p0=v0.x*v0.x, p1=v0.y*v0.y, p2=v0.z*v0.z, p3=v0.w*v0.w;
  float p4=v1.x*v1.x, p5=v1.y*v1.y, p6=v1.z*v1.z, p7=v1.w*v1.w;
  double s = (double)p0+(double)p1+(double)p2+(double)p3
           + (double)p4+(double)p5+(double)p6+(double)p7;
  #pragma unroll
  for (int m = 32; m >= 1; m >>= 1) s += __shfl_xor(s, m);
  if (lane == 0) s1[row] = (float)s;
  short8 o;
  o[0]=f2bf(v0.x); o[1]=f2bf(v0.y); o[2]=f2bf(v0.z); o[3]=f2bf(v0.w);
  o[4]=f2bf(v1.x); o[5]=f2bf(v1.y); o[6]=f2bf(v1.z); o[7]=f2bf(v1.w);
  const int mt = row >> 8, mi = row & 255;          // kc == lane
  *(short8*)(zh + ((((size_t)mt * 64 + lane) * 256) + mi) * 8) = o;
}

// pack emb -> eh bf16 fragment layout [nt(32)][kc(64)][ni(256)][j(8)], wave-per-row.
__global__ void vq_pack_e(const float* __restrict__ e, short* __restrict__ eh) {
  const int w = threadIdx.x >> 6, lane = threadIdx.x & 63;
  const int row = blockIdx.x * 4 + w;
  const float4* r = (const float4*)(e + (size_t)row * DIM);
  float4 v0 = r[lane * 2], v1 = r[lane * 2 + 1];
  short8 o;
  o[0]=f2bf(v0.x); o[1]=f2bf(v0.y); o[2]=f2bf(v0.z); o[3]=f2bf(v0.w);
  o[4]=f2bf(v1.x); o[5]=f2bf(v1.y); o[6]=f2bf(v1.z); o[7]=f2bf(v1.w);
  const int nt = row >> 8, ni = row & 255;
  *(short8*)(eh + ((((size_t)nt * 64 + lane) * 256) + ni) * 8) = o;
}

// MFMA GEMM + fused argmax/candidate epilogue. 256x256, BK=64, 8 waves (2m x 4n),
// wave tile 128x64, dbuf LDS, 4-phase-per-K-tile interleave (m201-style).
__global__ __launch_bounds__(512, 1)
void vq_mfma(const short* __restrict__ zh, const short* __restrict__ eh,
             float* __restrict__ pmax, int* __restrict__ pidx,
             int* __restrict__ cnt, int* __restrict__ extk) {
  __shared__ short8 lA[2][2048];   // [buf][kc(8)][mi(256)] : 32KB each
  __shared__ short8 lB[2][2048];   // [buf][kc(8)][ni(256)] : 32KB each

  // XCD-chunked swizzle (2048 blocks = 8 * 256, bijective)
  const int bid = blockIdx.x;
  const int xc = bid & 7, pos = bid >> 3;
  const int mt = xc * 8 + (pos & 7), nt = pos >> 3;

  const int n0 = nt * 256, m0 = mt * 256;
  const int tid = threadIdx.x;
  const int wid = tid >> 6, lane = tid & 63;
  const int wm = wid >> 2, wn = wid & 3;
  const int quad = lane >> 4, lc = lane & 15;

  f32x4 C[8][4];
  #pragma unroll
  for (int i = 0; i < 8; ++i)
    #pragma unroll
    for (int j = 0; j < 4; ++j) C[i][j] = (f32x4){0.f, 0.f, 0.f, 0.f};

  const char* gA = (const char*)zh + (size_t)mt * 262144;  // 64kc*256mi*16B panel
  const char* gB = (const char*)eh + (size_t)nt * 262144;

  // stage chunk-pair ch (8KB of A + 8KB of B) of K-tile tt into buf
  auto stage2 = [&](int buf, int tt, int ch) {
    const char* a = gA + (size_t)tt * 32768 + ch * 8192;
    const char* b = gB + (size_t)tt * 32768 + ch * 8192;
    GLDS16(a + tid * 16, (char*)&lA[buf][0] + ch * 8192 + tid * 16);
    GLDS16(b + tid * 16, (char*)&lB[buf][0] + ch * 8192 + tid * 16);
  };

  // prologue: all 4 chunk-pairs of tile 0; wait first 2 pairs (clusters 0,1 data)
  stage2(0, 0, 0); stage2(0, 0, 1); stage2(0, 0, 2); stage2(0, 0, 3);
  asm volatile("s_waitcnt vmcnt(4)" ::: "memory");
  __builtin_amdgcn_s_barrier();

  #pragma unroll
  for (int t = 0; t < 8; ++t) {
    const int p = t & 1;
    #pragma unroll
    for (int ph = 0; ph < 4; ++ph) {        // cluster = (s = ph>>1, mfh = ph&1)
      const int s = ph >> 1, mfh = ph & 1;
      const int kx = s * 4 + quad;
      // --- ds-load this cluster's register subtile (8 x ds_read_b128) ---
      short8 ra0 = lA[p][kx*256 + wm*128 + (mfh*4+0)*16 + lc];
      short8 ra1 = lA[p][kx*256 + wm*128 + (mfh*4+1)*16 + lc];
      short8 ra2 = lA[p][kx*256 + wm*128 + (mfh*4+2)*16 + lc];
      short8 ra3 = lA[p][kx*256 + wm*128 + (mfh*4+3)*16 + lc];
      short8 rb0 = lB[p][kx*256 + wn*64 +  0 + lc];
      short8 rb1 = lB[p][kx*256 + wn*64 + 16 + lc];
      short8 rb2 = lB[p][kx*256 + wn*64 + 32 + lc];
      short8 rb3 = lB[p][kx*256 + wn*64 + 48 + lc];
      // --- stage one chunk-pair of tile t+1 into the other buffer ---
      if (t < 7) stage2(p ^ 1, t + 1, ph);
      __builtin_amdgcn_s_barrier();
      asm volatile("s_waitcnt lgkmcnt(0)" ::: "memory");
      __builtin_amdgcn_sched_barrier(0);     // rule 18: pin MFMA after lgkmcnt
      __builtin_amdgcn_s_setprio(1);
      C[mfh*4+0][0] = __builtin_amdgcn_mfma_f32_16x16x32_bf16(ra0, rb0, C[mfh*4+0][0], 0,0,0);
      C[mfh*4+0][1] = __builtin_amdgcn_mfma_f32_16x16x32_bf16(ra0, rb1, C[mfh*4+0][1], 0,0,0);
      C[mfh*4+0][2] = __builtin_amdgcn_mfma_f32_16x16x32_bf16(ra0, rb2, C[mfh*4+0][2], 0,0,0);
      C[mfh*4+0][3] = __builtin_amdgcn_mfma_f32_16x16x32_bf16(ra0, rb3, C[mfh*4+0][3], 0,0,0);
      C[mfh*4+1][0] = __builtin_amdgcn_mfma_f32_16x16x32_bf16(ra1, rb0, C[mfh*4+1][0], 0,0,0);
      C[mfh*4+1][1] = __builtin_amdgcn_mfma_f32_16x16x32_bf16(ra1, rb1, C[mfh*4+1][1], 0,0,0);
      C[mfh*4+1][2] = __builtin_amdgcn_mfma_f32_16x16x32_bf16(ra1, rb2, C[mfh*4+1][2], 0,0,0);
      C[mfh*4+1][3] = __builtin_amdgcn_mfma_f32_16x16x32_bf16(ra1, rb3, C[mfh*4+1][3], 0,0,0);
      C[mfh*4+2][0] = __builtin_amdgcn_mfma_f32_16x16x32_bf16(ra2, rb0, C[mfh*4+2][0], 0,0,0);
      C[mfh*4+2][1] = __builtin_amdgcn_mfma_f32_16x16x32_bf16(ra2, rb1, C[mfh*4+2][1], 0,0,0);
      C[mfh*4+2][2] = __builtin_amdgcn_mfma_f32_16x16x32_bf16(ra2, rb2, C[mfh*4+2][2], 0,0,0);
      C[mfh*4+2][3] = __builtin_amdgcn_mfma_f32_16x16x32_bf16(ra2, rb3, C[mfh*4+2][3], 0,0,0);
      C[mfh*4+3][0] = __builtin_amdgcn_mfma_f32_16x16x32_bf16(ra3, rb0, C[mfh*4+3][0], 0,0,0);
      C[mfh*4+3][1] = __builtin_amdgcn_mfma_f32_16x16x32_bf16(ra3, rb1, C[mfh*4+3][1], 0,0,0);
      C[mfh*4+3][2] = __builtin_amdgcn_mfma_f32_16x16x32_bf16(ra3, rb2, C[mfh*4+3][2], 0,0,0);
      C[mfh*4+3][3] = __builtin_amdgcn_mfma_f32_16x16x32_bf16(ra3, rb3, C[mfh*4+3][3], 0,0,0);
      __builtin_amdgcn_s_setprio(0);
      // counted vmcnt at odd phases only (retire exactly one 2-pair group; never
      // drain mid-loop). Periodic: outstanding oscillates 4 <-> 8.
      if (ph == 1) {
        if (t < 7) { asm volatile("s_waitcnt vmcnt(4)" ::: "memory"); }
        else       { asm volatile("s_waitcnt vmcnt(0)" ::: "memory"); }
      } else if (ph == 3) {
        if (t < 7) { asm volatile("s_waitcnt vmcnt(4)" ::: "memory"); }
      }
      __builtin_amdgcn_s_barrier();
    }
  }
  __syncthreads();                            // epilogue aliases LDS

  // ---- epilogue: per-row argmax + candidate emission (proven machinery) ----
  float* cmbv = (float*)&lA[0][0];            // [256][4]
  int*   cmbk = (int*)(cmbv + 1024);
  float* bbv  = (float*)(cmbk + 1024);
  int*   bbk  = (int*)(bbv + 256);
  int*   lcnt = (int*)(bbk + 256);            // [256]

  #pragma unroll
  for (int mf = 0; mf < 8; ++mf)
    #pragma unroll
    for (int rr = 0; rr < 4; ++rr) {
      float bv = C[mf][0][rr]; int bn = 0;
      #pragma unroll
      for (int nf = 1; nf < 4; ++nf) {
        float v = C[mf][nf][rr];
        if (v > bv) { bv = v; bn = nf; }      // strict >: ties -> lowest nf (lowest k)
      }
      int bk = n0 + wn * 64 + bn * 16 + lc;
      #pragma unroll
      for (int m = 8; m >= 1; m >>= 1) {      // reduce 16 lanes (same quad)
        float vo = __shfl_xor(bv, m); int ko = __shfl_xor(bk, m);
        if (vo > bv || (vo == bv && ko < bk)) { bv = vo; bk = ko; }
      }
      if (lc == 0) {
        int row = wm * 128 + mf * 16 + quad * 4 + rr;
        cmbv[row * 4 + wn] = bv; cmbk[row * 4 + wn] = bk;
      }
    }
  __syncthreads();
  if (tid < 256) {
    float bv = cmbv[tid * 4 + 0]; int bk = cmbk[tid * 4 + 0];
    #pragma unroll
    for (int q = 1; q < 4; ++q) {             // ascending wn => ascending k: strict >
      float v = cmbv[tid * 4 + q]; int k = cmbk[tid * 4 + q];
      if (v > bv) { bv = v; bk = k; }
    }
    bbv[tid] = bv; bbk[tid] = bk;
    lcnt[tid] = 0;
    size_t rg = (size_t)(m0 + tid) * NKT + nt;
    pmax[rg] = bv; pidx[rg] = bk;
  }
  __syncthreads();
  // emit near-max extras (LDS counter; this block exclusively owns its rg rows)
  #pragma unroll
  for (int mf = 0; mf < 8; ++mf)
    #pragma unroll
    for (int nf = 0; nf < 4; ++nf)
      #pragma unroll
      for (int rr = 0; rr < 4; ++rr) {
        int row = wm * 128 + mf * 16 + quad * 4 + rr;
        float v = C[mf][nf][rr];
        if (v >= bbv[row] - MARGIN_A) {
          int k = n0 + wn * 64 + nf * 16 + lc;
          if (k != bbk[row]) {
            int slot = atomicAdd(&lcnt[row], 1);
            if (slot < 7) extk[((size_t)(m0 + row) * NKT + nt) * 7 + slot] = k;
          }
        }
      }
  __syncthreads();
  if (tid < 256) cnt[(size_t)(m0 + tid) * NKT + nt] = lcnt[tid];
}

// per-row: pick candidate tiles, EXACT fp32 recheck, gather/outputs/loss (unchanged)
__global__ void vq_finalize(const float* __restrict__ z, const float* __restrict__ emb,
                            const float* __restrict__ s1g,
                            const float* __restrict__ pmax, const int* __restrict__ pidx,
                            const int* __restrict__ cnt, const int* __restrict__ extk,
                            float* __restrict__ out, double* __restrict__ acc) {
  __shared__ int candk[4][40];
  __shared__ int lcnt[4];
  const int w = threadIdx.x >> 6, l = threadIdx.x & 63;
  const int row = blockIdx.x * 4 + w;
  const int l5 = l & 31;
  if (l == 0) lcnt[w] = 0;
  __syncthreads();
  const size_t rb = (size_t)row * NKT;
  float pv = pmax[rb + l5]; int pk = pidx[rb + l5];
  float gv = pv; int gk = pk;
  #pragma unroll
  for (int m = 16; m >= 1; m >>= 1) {
    float vo = __shfl_xor(gv, m); int ko = __shfl_xor(gk, m);
    if (vo > gv || (vo == gv && ko < gk)) { gv = vo; gk = ko; }
  }
  if (l < 32 && pv >= gv - MARGIN_A) {
    int c = cnt[rb + l5]; if (c > 7) c = 7;
    int slot = atomicAdd(&lcnt[w], 1 + c);
    if (slot < 40) candk[w][slot] = pk;
    for (int i = 0; i < c; ++i)
      if (slot + 1 + i < 40) candk[w][slot + 1 + i] = extk[(rb + l5) * 7 + i];
  }
  __syncthreads();
  int Cc = lcnt[w]; if (Cc > 40) Cc = 40;
  float qb = 1e30f; int kb = 0x7fffffff;
  const float s1 = s1g[row];
  const float* zr = z + (size_t)row * DIM;
  for (int ci = l5; ci < Cc; ci += 32) {    // lanes 32-63 duplicate (harmless)
    int k = candk[w][ci];
    const float* er = emb + (size_t)k * DIM;
    float d = 0.f;
    for (int i = 0; i < DIM; ++i) d = fmaf(zr[i], er[i], d);  // strict d-ascending
    float q = s1 - 2.f * d;                  // single-rounding quantize (2*d exact)
    if (q < qb || (q == qb && k < kb)) { qb = q; kb = k; }
  }
  #pragma unroll
  for (int m = 32; m >= 1; m >>= 1) {
    float qo = __shfl_xor(qb, m); int ko = __shfl_xor(kb, m);
    if (qo < qb || (qo == qb && ko < kb)) { qb = qo; kb = ko; }
  }
  const float4* zr4 = (const float4*)zr;
  const float4* qr4 = (const float4*)(emb + (size_t)kb * DIM);
  float4 zv0 = zr4[l * 2], zv1 = zr4[l * 2 + 1];
  float4 qv0 = qr4[l * 2], qv1 = qr4[l * 2 + 1];
  float ls = 0.f; float4 ov0, ov1;
  {
    const float* zp=(const float*)&zv0; const float* qp=(const float*)&qv0; float* op=(float*)&ov0;
    #pragma unroll
    for (int e = 0; e < 4; ++e) { float d = qp[e]-zp[e]; op[e] = zp[e]+d; ls += d*d; }
  }
  {
    const float* zp=(const float*)&zv1; const float* qp=(const float*)&qv1; float* op=(float*)&ov1;
    #pragma unroll
    for (int e = 0; e < 4; ++e) { float d = qp[e]-zp[e]; op[e] = zp[e]+d; ls += d*d; }
  }
  float4* orow = (float4*)(out + (size_t)row * DIM);
  orow[l * 2] = ov0; orow[l * 2 + 1] = ov1;
  #pragma unroll
  for (int m = 32; m >= 1; m >>= 1) ls += __shfl_xor(ls, m);
  if (l == 0) {
    out[(size_t)N_TOK * DIM + 1 + row] = (float)kb;
    atomicAdd(acc, (double)ls);
  }
}

__global__ void vq_loss(const double* __restrict__ acc, float* __restrict__ out) {
  out[(size_t)N_TOK * DIM] =
      (float)(*acc * (1.0 + (double)BETA) / ((double)N_TOK * (double)DIM));
}

extern "C" void kernel_launch(void* const* d_in, const int* in_sizes, int n_in,
                              void* d_out, int out_size, void* d_ws, size_t ws_size,
                              hipStream_t stream) {
  const float* z   = (const float*)d_in[0];
  const float* emb = (const float*)d_in[1];
  float* out = (float*)d_out;
  char* ws = (char*)d_ws;
  double* acc  = (double*)(ws + WS_ACC);
  int*    cnt  = (int*)(ws + WS_CNT);
  float*  pmax = (float*)(ws + WS_PMAX);
  int*    pidx = (int*)(ws + WS_PIDX);
  int*    extk = (int*)(ws + WS_EXTK);
  float*  s1   = (float*)(ws + WS_S1);
  short*  zh   = (short*)(ws + WS_ZH);
  short*  eh   = (short*)(ws + WS_EH);

  vq_pack_z<<<N_TOK / 4, 256, 0, stream>>>(z, zh, s1, acc);
  vq_pack_e<<<NEMB / 4, 256, 0, stream>>>(emb, eh);
  vq_mfma<<<(N_TOK / 256) * (NEMB / 256), 512, 0, stream>>>(zh, eh, pmax, pidx, cnt, extk);
  vq_finalize<<<N_TOK / 4, 256, 0, stream>>>(z, emb, s1, pmax, pidx, cnt, extk, out, acc);
  vq_loss<<<1, 1, 0, stream>>>(acc, out);
}

// Round 10
// 461.087 us; speedup vs baseline: 1.3416x; 1.1736x over previous
//
#include <hip/hip_runtime.h>

// VectorQuantizer: z [16,1024,512] f32, emb [8192,512] f32
// out: [z_q_st (16384*512 f32)][total_loss (1 f32)][idx as f32 (16384)]
//
// bf16 MFMA computes approx dot(z,emb) (argmax acc == argmin dist); epilogue keeps
// per-(row,256-tile) max + candidates within MARGIN_A; finalize rechecks candidates
// with the EXACT fp32 d-ascending fmaf chain + q = fl(s1-2*dot) quantization
// (bit-identical to the round-2 kernel that passed absmax 0), lowest-index ties.
//
// Round 10: TLP-first. All 1-block/CU schedule variants plateaued at 368-413us
// (MfmaUtil ~15%, every pipe <25% loaded => serialization, not throughput). The
// only faster GEMM (R3, 330us) had 2 independent blocks/CU -- m97's mechanism.
// So: 64x256 tile, 4-wave blocks (C=64/wave, ~140 combined regs => 3 waves/SIMD),
// single-buffered 40KB LDS => 3 blocks/CU. Plain 2-syncthreads K-loop; cross-block
// overlap hides stage/drain latency. No setprio, no swizzle.

#define N_TOK 16384
#define DIM   512
#define NEMB  8192
#define BETA  0.25f
#define NKT   32              // 8192 / 256 n-tiles
#define MARGIN_A 2.0e-4f      // in acc(dot) units; plateau 3.05e-5 + bf16 err (14-sigma)

using short8 = __attribute__((ext_vector_type(8))) short;
using f32x4  = __attribute__((ext_vector_type(4))) float;

// ---- ws layout (bytes), total ~46.2 MB ----
#define WS_ACC  0
#define WS_CNT  64
#define WS_PMAX (WS_CNT  + N_TOK*NKT*4)
#define WS_PIDX (WS_PMAX + N_TOK*NKT*4)
#define WS_EXTK (WS_PIDX + N_TOK*NKT*4)
#define WS_S1   (WS_EXTK + N_TOK*NKT*7*4)
#define WS_ZH   (WS_S1   + N_TOK*4)
#define WS_EH   (WS_ZH   + N_TOK*DIM*2)

__device__ inline short f2bf(float f) {   // RNE float->bf16
  unsigned u = __builtin_bit_cast(unsigned, f);
  u += 0x7fffu + ((u >> 16) & 1u);
  return (short)(u >> 16);
}

#define GLDS16(g, l) __builtin_amdgcn_global_load_lds( \
    (const __attribute__((address_space(1))) void*)(g), \
    (__attribute__((address_space(3))) void*)(l), 16, 0, 0)

// pack z -> zh bf16 fragment layout [mt(256)][kc(64)][mi(64)][j(8)], fused s1.
// Also zeroes the loss accumulator (block 0, thread 0).
__global__ void vq_pack_z(const float* __restrict__ z, short* __restrict__ zh,
                          float* __restrict__ s1, double* __restrict__ acc) {
  if (blockIdx.x == 0 && threadIdx.x == 0) *acc = 0.0;
  const int w = threadIdx.x >> 6, lane = threadIdx.x & 63;
  const int row = blockIdx.x * 4 + w;
  const float4* r = (const float4*)(z + (size_t)row * DIM);
  float4 v0 = r[lane * 2], v1 = r[lane * 2 + 1];
  // s1: bit-identical to the passing round-2 path (same products, order, reduce)
  float p0=v0.x*v0.x, p1=v0.y*v0.y, p2=v0.z*v0.z, p3=v0.w*v0.w;
  float p4=v1.x*v1.x, p5=v1.y*v1.y, p6=v1.z*v1.z, p7=v1.w*v1.w;
  double s = (double)p0+(double)p1+(double)p2+(double)p3
           + (double)p4+(double)p5+(double)p6+(double)p7;
  #pragma unroll
  for (int m = 32; m >= 1; m >>= 1) s += __shfl_xor(s, m);
  if (lane == 0) s1[row] = (float)s;
  short8 o;
  o[0]=f2bf(v0.x); o[1]=f2bf(v0.y); o[2]=f2bf(v0.z); o[3]=f2bf(v0.w);
  o[4]=f2bf(v1.x); o[5]=f2bf(v1.y); o[6]=f2bf(v1.z); o[7]=f2bf(v1.w);
  const int mt = row >> 6, mi = row & 63;           // kc == lane
  *(short8*)(zh + ((((size_t)mt * 64 + lane) * 64) + mi) * 8) = o;
}

// pack emb -> eh bf16 fragment layout [nt(32)][kc(64)][ni(256)][j(8)], wave-per-row.
__global__ void vq_pack_e(const float* __restrict__ e, short* __restrict__ eh) {
  const int w = threadIdx.x >> 6, lane = threadIdx.x & 63;
  const int row = blockIdx.x * 4 + w;
  const float4* r = (const float4*)(e + (size_t)row * DIM);
  float4 v0 = r[lane * 2], v1 = r[lane * 2 + 1];
  short8 o;
  o[0]=f2bf(v0.x); o[1]=f2bf(v0.y); o[2]=f2bf(v0.z); o[3]=f2bf(v0.w);
  o[4]=f2bf(v1.x); o[5]=f2bf(v1.y); o[6]=f2bf(v1.z); o[7]=f2bf(v1.w);
  const int nt = row >> 8, ni = row & 255;
  *(short8*)(eh + ((((size_t)nt * 64 + lane) * 256) + ni) * 8) = o;
}

// MFMA GEMM + fused argmax/candidate epilogue.
// Block = 64 rows x 256 cols, 4 waves (1m x 4n), wave tile 64x64, BK=64,
// single-buffered 40KB LDS => 3 blocks/CU. grid = (mt 256, nt 32).
__global__ __launch_bounds__(256, 3)
void vq_mfma(const short* __restrict__ zh, const short* __restrict__ eh,
             float* __restrict__ pmax, int* __restrict__ pidx,
             int* __restrict__ cnt, int* __restrict__ extk) {
  __shared__ short8 lA[8 * 64];    // [kc(8)][mi(64)]  : 8KB
  __shared__ short8 lB[8 * 256];   // [kc(8)][ni(256)] : 32KB

  const int mt = blockIdx.x, nt = blockIdx.y;
  const int n0 = nt * 256, m0 = mt * 64;
  const int tid = threadIdx.x;
  const int wid = tid >> 6, lane = tid & 63;        // wid == wn (1m x 4n)
  const int quad = lane >> 4, lc = lane & 15;

  f32x4 C[4][4];
  #pragma unroll
  for (int i = 0; i < 4; ++i)
    #pragma unroll
    for (int j = 0; j < 4; ++j) C[i][j] = (f32x4){0.f, 0.f, 0.f, 0.f};

  const char* gA = (const char*)zh + (size_t)mt * 65536;   // 64kc*64mi*16B panel
  const char* gB = (const char*)eh + (size_t)nt * 262144;  // 64kc*256ni*16B panel

  for (int t = 0; t < 8; ++t) {
    // stage K-tile t: A 8KB (2 chunks/thread) + B 32KB (8 chunks/thread)
    {
      const char* a = gA + (size_t)t * 8192;
      const char* b = gB + (size_t)t * 32768;
      GLDS16(a + tid * 16,        (char*)&lA[0] + tid * 16);
      GLDS16(a + 4096 + tid * 16, (char*)&lA[0] + 4096 + tid * 16);
      #pragma unroll
      for (int i = 0; i < 8; ++i)
        GLDS16(b + i * 4096 + tid * 16, (char*)&lB[0] + i * 4096 + tid * 16);
    }
    __syncthreads();                          // vmcnt(0) drain + barrier (compiler)
    #pragma unroll
    for (int s = 0; s < 2; ++s) {             // two K=32 slots per BK=64 tile
      const int kx = s * 4 + quad;
      short8 a0 = lA[kx * 64 +  0 + lc];
      short8 a1 = lA[kx * 64 + 16 + lc];
      short8 a2 = lA[kx * 64 + 32 + lc];
      short8 a3 = lA[kx * 64 + 48 + lc];
      short8 b0 = lB[kx * 256 + wid * 64 +  0 + lc];
      short8 b1 = lB[kx * 256 + wid * 64 + 16 + lc];
      short8 b2 = lB[kx * 256 + wid * 64 + 32 + lc];
      short8 b3 = lB[kx * 256 + wid * 64 + 48 + lc];
      C[0][0] = __builtin_amdgcn_mfma_f32_16x16x32_bf16(a0, b0, C[0][0], 0, 0, 0);
      C[0][1] = __builtin_amdgcn_mfma_f32_16x16x32_bf16(a0, b1, C[0][1], 0, 0, 0);
      C[0][2] = __builtin_amdgcn_mfma_f32_16x16x32_bf16(a0, b2, C[0][2], 0, 0, 0);
      C[0][3] = __builtin_amdgcn_mfma_f32_16x16x32_bf16(a0, b3, C[0][3], 0, 0, 0);
      C[1][0] = __builtin_amdgcn_mfma_f32_16x16x32_bf16(a1, b0, C[1][0], 0, 0, 0);
      C[1][1] = __builtin_amdgcn_mfma_f32_16x16x32_bf16(a1, b1, C[1][1], 0, 0, 0);
      C[1][2] = __builtin_amdgcn_mfma_f32_16x16x32_bf16(a1, b2, C[1][2], 0, 0, 0);
      C[1][3] = __builtin_amdgcn_mfma_f32_16x16x32_bf16(a1, b3, C[1][3], 0, 0, 0);
      C[2][0] = __builtin_amdgcn_mfma_f32_16x16x32_bf16(a2, b0, C[2][0], 0, 0, 0);
      C[2][1] = __builtin_amdgcn_mfma_f32_16x16x32_bf16(a2, b1, C[2][1], 0, 0, 0);
      C[2][2] = __builtin_amdgcn_mfma_f32_16x16x32_bf16(a2, b2, C[2][2], 0, 0, 0);
      C[2][3] = __builtin_amdgcn_mfma_f32_16x16x32_bf16(a2, b3, C[2][3], 0, 0, 0);
      C[3][0] = __builtin_amdgcn_mfma_f32_16x16x32_bf16(a3, b0, C[3][0], 0, 0, 0);
      C[3][1] = __builtin_amdgcn_mfma_f32_16x16x32_bf16(a3, b1, C[3][1], 0, 0, 0);
      C[3][2] = __builtin_amdgcn_mfma_f32_16x16x32_bf16(a3, b2, C[3][2], 0, 0, 0);
      C[3][3] = __builtin_amdgcn_mfma_f32_16x16x32_bf16(a3, b3, C[3][3], 0, 0, 0);
    }
    __syncthreads();                          // readers done before next overwrite
  }

  // ---- epilogue (aliases lA/lB; proven absmax-0 machinery) ----
  float* cmbv = (float*)&lA[0];               // [64][4]
  int*   cmbk = (int*)(cmbv + 256);
  float* bbv  = (float*)(cmbk + 256);
  int*   bbk  = (int*)(bbv + 64);
  int*   lcnt = (int*)(bbk + 64);             // [64]

  // per-row argmax over this 256-wide tile; C/D layout: row=quad*4+rr, col=lc
  #pragma unroll
  for (int mf = 0; mf < 4; ++mf)
    #pragma unroll
    for (int rr = 0; rr < 4; ++rr) {
      float bv = C[mf][0][rr]; int bn = 0;
      #pragma unroll
      for (int nf = 1; nf < 4; ++nf) {
        float v = C[mf][nf][rr];
        if (v > bv) { bv = v; bn = nf; }      // strict >: ties -> lowest nf (lowest k)
      }
      int bk = n0 + wid * 64 + bn * 16 + lc;
      #pragma unroll
      for (int m = 8; m >= 1; m >>= 1) {      // reduce 16 lanes (same quad)
        float vo = __shfl_xor(bv, m); int ko = __shfl_xor(bk, m);
        if (vo > bv || (vo == bv && ko < bk)) { bv = vo; bk = ko; }
      }
      if (lc == 0) {
        int row = mf * 16 + quad * 4 + rr;
        cmbv[row * 4 + wid] = bv; cmbk[row * 4 + wid] = bk;
      }
    }
  __syncthreads();
  if (tid < 64) {
    float bv = cmbv[tid * 4 + 0]; int bk = cmbk[tid * 4 + 0];
    #pragma unroll
    for (int q = 1; q < 4; ++q) {             // ascending wid => ascending k: strict >
      float v = cmbv[tid * 4 + q]; int k = cmbk[tid * 4 + q];
      if (v > bv) { bv = v; bk = k; }
    }
    bbv[tid] = bv; bbk[tid] = bk;
    lcnt[tid] = 0;
    size_t rg = (size_t)(m0 + tid) * NKT + nt;
    pmax[rg] = bv; pidx[rg] = bk;
  }
  __syncthreads();
  // emit near-max extras (LDS counter; this block exclusively owns its rg rows)
  #pragma unroll
  for (int mf = 0; mf < 4; ++mf)
    #pragma unroll
    for (int nf = 0; nf < 4; ++nf)
      #pragma unroll
      for (int rr = 0; rr < 4; ++rr) {
        int row = mf * 16 + quad * 4 + rr;
        float v = C[mf][nf][rr];
        if (v >= bbv[row] - MARGIN_A) {
          int k = n0 + wid * 64 + nf * 16 + lc;
          if (k != bbk[row]) {
            int slot = atomicAdd(&lcnt[row], 1);
            if (slot < 7) extk[((size_t)(m0 + row) * NKT + nt) * 7 + slot] = k;
          }
        }
      }
  __syncthreads();
  if (tid < 64) cnt[(size_t)(m0 + tid) * NKT + nt] = lcnt[tid];
}

// per-row: pick candidate tiles, EXACT fp32 recheck, gather/outputs/loss (unchanged)
__global__ void vq_finalize(const float* __restrict__ z, const float* __restrict__ emb,
                            const float* __restrict__ s1g,
                            const float* __restrict__ pmax, const int* __restrict__ pidx,
                            const int* __restrict__ cnt, const int* __restrict__ extk,
                            float* __restrict__ out, double* __restrict__ acc) {
  __shared__ int candk[4][40];
  __shared__ int lcnt[4];
  const int w = threadIdx.x >> 6, l = threadIdx.x & 63;
  const int row = blockIdx.x * 4 + w;
  const int l5 = l & 31;
  if (l == 0) lcnt[w] = 0;
  __syncthreads();
  const size_t rb = (size_t)row * NKT;
  float pv = pmax[rb + l5]; int pk = pidx[rb + l5];
  float gv = pv; int gk = pk;
  #pragma unroll
  for (int m = 16; m >= 1; m >>= 1) {
    float vo = __shfl_xor(gv, m); int ko = __shfl_xor(gk, m);
    if (vo > gv || (vo == gv && ko < gk)) { gv = vo; gk = ko; }
  }
  if (l < 32 && pv >= gv - MARGIN_A) {
    int c = cnt[rb + l5]; if (c > 7) c = 7;
    int slot = atomicAdd(&lcnt[w], 1 + c);
    if (slot < 40) candk[w][slot] = pk;
    for (int i = 0; i < c; ++i)
      if (slot + 1 + i < 40) candk[w][slot + 1 + i] = extk[(rb + l5) * 7 + i];
  }
  __syncthreads();
  int Cc = lcnt[w]; if (Cc > 40) Cc = 40;
  float qb = 1e30f; int kb = 0x7fffffff;
  const float s1 = s1g[row];
  const float* zr = z + (size_t)row * DIM;
  for (int ci = l5; ci < Cc; ci += 32) {    // lanes 32-63 duplicate (harmless)
    int k = candk[w][ci];
    const float* er = emb + (size_t)k * DIM;
    float d = 0.f;
    for (int i = 0; i < DIM; ++i) d = fmaf(zr[i], er[i], d);  // strict d-ascending
    float q = s1 - 2.f * d;                  // single-rounding quantize (2*d exact)
    if (q < qb || (q == qb && k < kb)) { qb = q; kb = k; }
  }
  #pragma unroll
  for (int m = 32; m >= 1; m >>= 1) {
    float qo = __shfl_xor(qb, m); int ko = __shfl_xor(kb, m);
    if (qo < qb || (qo == qb && ko < kb)) { qb = qo; kb = ko; }
  }
  const float4* zr4 = (const float4*)zr;
  const float4* qr4 = (const float4*)(emb + (size_t)kb * DIM);
  float4 zv0 = zr4[l * 2], zv1 = zr4[l * 2 + 1];
  float4 qv0 = qr4[l * 2], qv1 = qr4[l * 2 + 1];
  float ls = 0.f; float4 ov0, ov1;
  {
    const float* zp=(const float*)&zv0; const float* qp=(const float*)&qv0; float* op=(float*)&ov0;
    #pragma unroll
    for (int e = 0; e < 4; ++e) { float d = qp[e]-zp[e]; op[e] = zp[e]+d; ls += d*d; }
  }
  {
    const float* zp=(const float*)&zv1; const float* qp=(const float*)&qv1; float* op=(float*)&ov1;
    #pragma unroll
    for (int e = 0; e < 4; ++e) { float d = qp[e]-zp[e]; op[e] = zp[e]+d; ls += d*d; }
  }
  float4* orow = (float4*)(out + (size_t)row * DIM);
  orow[l * 2] = ov0; orow[l * 2 + 1] = ov1;
  #pragma unroll
  for (int m = 32; m >= 1; m >>= 1) ls += __shfl_xor(ls, m);
  if (l == 0) {
    out[(size_t)N_TOK * DIM + 1 + row] = (float)kb;
    atomicAdd(acc, (double)ls);
  }
}

__global__ void vq_loss(const double* __restrict__ acc, float* __restrict__ out) {
  out[(size_t)N_TOK * DIM] =
      (float)(*acc * (1.0 + (double)BETA) / ((double)N_TOK * (double)DIM));
}

extern "C" void kernel_launch(void* const* d_in, const int* in_sizes, int n_in,
                              void* d_out, int out_size, void* d_ws, size_t ws_size,
                              hipStream_t stream) {
  const float* z   = (const float*)d_in[0];
  const float* emb = (const float*)d_in[1];
  float* out = (float*)d_out;
  char* ws = (char*)d_ws;
  double* acc  = (double*)(ws + WS_ACC);
  int*    cnt  = (int*)(ws + WS_CNT);
  float*  pmax = (float*)(ws + WS_PMAX);
  int*    pidx = (int*)(ws + WS_PIDX);
  int*    extk = (int*)(ws + WS_EXTK);
  float*  s1   = (float*)(ws + WS_S1);
  short*  zh   = (short*)(ws + WS_ZH);
  short*  eh   = (short*)(ws + WS_EH);

  vq_pack_z<<<N_TOK / 4, 256, 0, stream>>>(z, zh, s1, acc);
  vq_pack_e<<<NEMB / 4, 256, 0, stream>>>(emb, eh);
  vq_mfma<<<dim3(N_TOK / 64, NEMB / 256), 256, 0, stream>>>(zh, eh, pmax, pidx, cnt, extk);
  vq_finalize<<<N_TOK / 4, 256, 0, stream>>>(z, emb, s1, pmax, pidx, cnt, extk, out, acc);
  vq_loss<<<1, 1, 0, stream>>>(acc, out);
}